// Round 8
// baseline (121.149 us; speedup 1.0000x reference)
//
#include <hip/hip_runtime.h>
#include <math.h>

#define N_RAYS 65536
#define T_SAMPLES 128
#define HID 16

#define RAYS_PER_BLOCK 32
#define CHUNKS 8
#define CHUNK_LEN (T_SAMPLES / CHUNKS)   // 16 samples per chunk

#define L2E 1.4426950408889634f

// block=256 (32 rays x 8 chunks), launch_bounds(256,4) -> VGPR cap 128.
// R5 lesson: never cap VGPR below the ~80 live set (spill disaster).
// Scalar fp32 only: v_fma_f32 is full-rate on CDNA4; v_pk_fma_f32 is
// half-issue-rate (R4/R6 neutrality) -> packed fp32 buys nothing.
// Fully unrolled chunk with register-prefetched noise: no LDS in the hot
// loop, no address arithmetic, minimal glue.
__global__ __launch_bounds__(256, 4) void radiance_kernel(
    const float* __restrict__ o,
    const float* __restrict__ d,
    const float* __restrict__ tnear,
    const float* __restrict__ tfar,
    const float* __restrict__ noise,
    const float* __restrict__ W1,
    const float* __restrict__ b1,
    const float* __restrict__ w_sigma,
    const float* __restrict__ W_rgb,
    float* __restrict__ out)
{
    __shared__ float s_lt[CHUNKS * RAYS_PER_BLOCK];        // [8][32]
    __shared__ float s_acc[CHUNKS * 5 * RAYS_PER_BLOCK];   // [8][5][32]

    const int ridx  = threadIdx.x & 31;   // ray within block
    const int chunk = threadIdx.x >> 5;   // 0..7
    const int ray   = blockIdx.x * RAYS_PER_BLOCK + ridx;
    const int t0    = chunk * CHUNK_LEN;

    // ---- prefetch this chunk's 17 noise values into registers ----
    // (16 samples + next-chunk boundary; chunk 7's boundary is the zero
    //  sentinel -> ts_boundary = tn + sc*128 = tf)
    float nzv[CHUNK_LEN + 1];
#pragma unroll
    for (int k = 0; k <= CHUNK_LEN; ++k) {
        const int tt = t0 + k;
        const int tc = tt < T_SAMPLES ? tt : T_SAMPLES - 1;  // clamp addr (chunk 7, k=16)
        nzv[k] = noise[(size_t)tc * N_RAYS + ray];
    }
    if (t0 + CHUNK_LEN >= T_SAMPLES) nzv[CHUNK_LEN] = 0.0f;

    // ---- per-ray setup (duplicated across the 8 chunk-groups) ----
    const float ox = o[ray*3+0], oy = o[ray*3+1], oz = o[ray*3+2];
    const float dx = d[ray*3+0], dy = d[ray*3+1], dz = d[ray*3+2];
    const float tn = tnear[ray];
    const float tf = tfar[ray];
    const float dnorm = sqrtf(dx*dx + dy*dy + dz*dz);
    const float sc = (tf - tn) * (1.0f / (float)T_SAMPLES);

    // Hoisted MLP layer 1: h_j(ts) = relu(A_j + ts*B_j)
    float A[HID], B[HID];
#pragma unroll
    for (int j = 0; j < HID; ++j) {
        const float w0 = W1[0*HID + j], w1 = W1[1*HID + j], w2 = W1[2*HID + j];
        A[j] = fmaf(ox, w0, fmaf(oy, w1, fmaf(oz, w2, b1[j])));
        B[j] = fmaf(dx, w0, fmaf(dy, w1, dz * w2));
    }
    // Output weights: uniform-indexed -> SGPRs
    float WS[HID], WR[HID], WG[HID], WB[HID];
#pragma unroll
    for (int j = 0; j < HID; ++j) {
        WS[j] = w_sigma[j];
        WR[j] = W_rgb[j*3+0];
        WG[j] = W_rgb[j*3+1];
        WB[j] = W_rgb[j*3+2];
    }

    const float t0f = (float)t0;
    float ts = fmaf(sc, t0f + nzv[0], tn);

    float lt = 1.0f;
    float cr = 0.f, cg = 0.f, cb = 0.f, cd = 0.f, ca = 0.f;

#pragma unroll
    for (int k = 0; k < CHUNK_LEN; ++k) {
        // next sample position: (k+1) is a compile-time float literal
        const float ts_next = fmaf(sc, t0f + (float)(k + 1) + nzv[k + 1], tn);

        // ---- MLP (scalar fp32, full-rate) ----
        float sp = 0.f, rr = 0.f, gg = 0.f, bb = 0.f;
#pragma unroll
        for (int j = 0; j < HID; ++j) {
            const float h = fmaxf(fmaf(ts, B[j], A[j]), 0.0f);
            sp = fmaf(h, WS[j], sp);
            rr = fmaf(h, WR[j], rr);
            gg = fmaf(h, WG[j], gg);
            bb = fmaf(h, WB[j], bb);
        }

        // softplus -> l2 = log2(1+exp(sp)) (stable)
        const float e  = __builtin_amdgcn_exp2f(-fabsf(sp) * L2E);
        const float l2 = fmaf(fmaxf(sp, 0.0f), L2E, __builtin_amdgcn_logf(1.0f + e));
        // et = exp(-sigma*delta*dnorm) = 2^((ts - ts_next)*dnorm*l2)  (arg < 0)
        const float et = __builtin_amdgcn_exp2f((ts - ts_next) * dnorm * l2);

        // sigmoids
        const float r = __builtin_amdgcn_rcpf(1.0f + __builtin_amdgcn_exp2f(-rr * L2E));
        const float g = __builtin_amdgcn_rcpf(1.0f + __builtin_amdgcn_exp2f(-gg * L2E));
        const float b = __builtin_amdgcn_rcpf(1.0f + __builtin_amdgcn_exp2f(-bb * L2E));

        // integration: w = lt*(1-et) = fma(-lt, et, lt)
        const float w = fmaf(-lt, et, lt);
        cr = fmaf(w, r, cr);
        cg = fmaf(w, g, cg);
        cb = fmaf(w, b, cb);
        cd = fmaf(w, ts, cd);
        ca += w;
        lt *= et;
        ts = ts_next;
    }

    // ---- combine chunks ----
    s_lt[chunk * RAYS_PER_BLOCK + ridx] = lt;
    s_acc[(chunk * 5 + 0) * RAYS_PER_BLOCK + ridx] = cr;
    s_acc[(chunk * 5 + 1) * RAYS_PER_BLOCK + ridx] = cg;
    s_acc[(chunk * 5 + 2) * RAYS_PER_BLOCK + ridx] = cb;
    s_acc[(chunk * 5 + 3) * RAYS_PER_BLOCK + ridx] = cd;
    s_acc[(chunk * 5 + 4) * RAYS_PER_BLOCK + ridx] = ca;
    __syncthreads();

    if (threadIdx.x < RAYS_PER_BLOCK) {
        float scale = 1.0f;
        float a0 = 0.f, a1 = 0.f, a2 = 0.f, a3 = 0.f, a4 = 0.f;
#pragma unroll
        for (int c = 0; c < CHUNKS; ++c) {
            a0 = fmaf(scale, s_acc[(c * 5 + 0) * RAYS_PER_BLOCK + ridx], a0);
            a1 = fmaf(scale, s_acc[(c * 5 + 1) * RAYS_PER_BLOCK + ridx], a1);
            a2 = fmaf(scale, s_acc[(c * 5 + 2) * RAYS_PER_BLOCK + ridx], a2);
            a3 = fmaf(scale, s_acc[(c * 5 + 3) * RAYS_PER_BLOCK + ridx], a3);
            a4 = fmaf(scale, s_acc[(c * 5 + 4) * RAYS_PER_BLOCK + ridx], a4);
            scale *= s_lt[c * RAYS_PER_BLOCK + ridx];
        }
        out[ray*5+0] = a0;
        out[ray*5+1] = a1;
        out[ray*5+2] = a2;
        out[ray*5+3] = a3;
        out[ray*5+4] = a4;
    }
}

extern "C" void kernel_launch(void* const* d_in, const int* in_sizes, int n_in,
                              void* d_out, int out_size, void* d_ws, size_t ws_size,
                              hipStream_t stream) {
    const float* o       = (const float*)d_in[0];
    const float* d       = (const float*)d_in[1];
    const float* tnear   = (const float*)d_in[2];
    const float* tfar    = (const float*)d_in[3];
    const float* noise   = (const float*)d_in[4];
    const float* W1      = (const float*)d_in[5];
    const float* b1      = (const float*)d_in[6];
    const float* w_sigma = (const float*)d_in[7];
    const float* W_rgb   = (const float*)d_in[8];
    float* out = (float*)d_out;

    dim3 block(RAYS_PER_BLOCK * CHUNKS);           // 256
    dim3 grid(N_RAYS / RAYS_PER_BLOCK);            // 2048
    hipLaunchKernelGGL(radiance_kernel, grid, block, 0, stream,
                       o, d, tnear, tfar, noise, W1, b1, w_sigma, W_rgb, out);
}